// Round 1
// baseline (418.436 us; speedup 1.0000x reference)
//
#include <hip/hip_runtime.h>

#define D 512
#define DOUT 64

// ---------------- CSR build ----------------

__global__ void degree_kernel(const int* __restrict__ dst, int* __restrict__ deg, int nE) {
    int e = blockIdx.x * blockDim.x + threadIdx.x;
    if (e < nE) atomicAdd(&deg[dst[e]], 1);
}

// single-block exclusive scan over n (<= ~1M) ints; rp gets n+1 entries
__global__ __launch_bounds__(1024) void exscan_kernel(const int* __restrict__ deg,
                                                      int* __restrict__ rp, int n) {
    __shared__ int wtot[16];
    __shared__ int carry;
    int tid = threadIdx.x, lane = tid & 63, wid = tid >> 6;
    if (tid == 0) carry = 0;
    __syncthreads();
    for (int base = 0; base < n; base += 1024) {
        int i = base + tid;
        int v = (i < n) ? deg[i] : 0;
        int s = v;
        #pragma unroll
        for (int off = 1; off < 64; off <<= 1) {
            int t = __shfl_up(s, off, 64);
            if (lane >= off) s += t;
        }
        if (lane == 63) wtot[wid] = s;
        __syncthreads();
        if (wid == 0 && lane < 16) {
            int wv = wtot[lane];
            int ws_ = wv;
            #pragma unroll
            for (int off = 1; off < 16; off <<= 1) {
                int t = __shfl_up(ws_, off, 64);
                if (lane >= off) ws_ += t;
            }
            wtot[lane] = ws_ - wv;  // exclusive wave-offset
        }
        __syncthreads();
        int excl = carry + wtot[wid] + (s - v);
        if (i < n) rp[i] = excl;
        __syncthreads();
        if (tid == 1023) carry = excl + v;  // running total
        __syncthreads();
    }
    if (tid == 0) rp[n] = carry;
}

__global__ void fill_kernel(const int* __restrict__ src, const int* __restrict__ dst,
                            int* __restrict__ cursor, int* __restrict__ col, int nE) {
    int e = blockIdx.x * blockDim.x + threadIdx.x;
    if (e < nE) {
        int d = dst[e];
        int p = atomicAdd(&cursor[d], 1);
        col[p] = src[e];
    }
}

// ---------------- propagate: out[n,:] = sum over incoming edges of xin[src,:] ----------------
// one block (128 threads) per node, float4 per thread (128*4 = 512 feats)
__global__ __launch_bounds__(128) void propagate_kernel(const float* __restrict__ xin,
        const int* __restrict__ row_ptr, const int* __restrict__ col,
        float* __restrict__ out) {
    int n = blockIdx.x;
    int t = threadIdx.x;
    int s0 = row_ptr[n], s1 = row_ptr[n + 1];
    float4 acc = make_float4(0.f, 0.f, 0.f, 0.f);
    for (int e = s0; e < s1; ++e) {
        int s = col[e];
        float4 v = ((const float4*)(xin + (size_t)s * D))[t];
        acc.x += v.x; acc.y += v.y; acc.z += v.z; acc.w += v.w;
    }
    ((float4*)(out + (size_t)n * D))[t] = acc;
}

// ---------------- NT GEMM: C[m,n] = sum_k A[m,k]*B[n,k], optional relu ----------------
// 64x64 tile, 256 threads, 4x4 micro-tile, K-major LDS so inner loop is ds_read_b128
#define TM 64
#define TN 64
#define BK 16
#define LDP (TM + 4)

__global__ __launch_bounds__(256) void gemm_nt_kernel(const float* __restrict__ A,
        const float* __restrict__ B, float* __restrict__ C,
        int M, int N, int K, int do_relu) {
    __shared__ float As[BK][LDP];
    __shared__ float Bs[BK][LDP];
    int tid = threadIdx.x;
    int tx = tid & 15, ty = tid >> 4;
    int m0 = blockIdx.y * TM, n0 = blockIdx.x * TN;
    int lr = tid >> 2;           // 0..63: tile row
    int lc = (tid & 3) * 4;      // 0,4,8,12: k-offset within tile
    float acc[4][4] = {};
    for (int k0 = 0; k0 < K; k0 += BK) {
        int am = m0 + lr;
        float4 av = (am < M) ? *(const float4*)(A + (size_t)am * K + k0 + lc)
                             : make_float4(0.f, 0.f, 0.f, 0.f);
        float4 bv = *(const float4*)(B + (size_t)(n0 + lr) * K + k0 + lc);
        As[lc + 0][lr] = av.x; As[lc + 1][lr] = av.y;
        As[lc + 2][lr] = av.z; As[lc + 3][lr] = av.w;
        Bs[lc + 0][lr] = bv.x; Bs[lc + 1][lr] = bv.y;
        Bs[lc + 2][lr] = bv.z; Bs[lc + 3][lr] = bv.w;
        __syncthreads();
        #pragma unroll
        for (int kk = 0; kk < BK; ++kk) {
            float4 a4 = *(const float4*)&As[kk][ty * 4];
            float4 b4 = *(const float4*)&Bs[kk][tx * 4];
            float a[4] = {a4.x, a4.y, a4.z, a4.w};
            float b[4] = {b4.x, b4.y, b4.z, b4.w};
            #pragma unroll
            for (int i = 0; i < 4; ++i)
                #pragma unroll
                for (int j = 0; j < 4; ++j)
                    acc[i][j] = fmaf(a[i], b[j], acc[i][j]);
        }
        __syncthreads();
    }
    #pragma unroll
    for (int i = 0; i < 4; ++i) {
        int m = m0 + ty * 4 + i;
        if (m < M) {
            float4 v;
            v.x = acc[i][0]; v.y = acc[i][1]; v.z = acc[i][2]; v.w = acc[i][3];
            if (do_relu) {
                v.x = fmaxf(v.x, 0.f); v.y = fmaxf(v.y, 0.f);
                v.z = fmaxf(v.z, 0.f); v.w = fmaxf(v.w, 0.f);
            }
            *(float4*)(C + (size_t)m * N + n0 + tx * 4) = v;
        }
    }
}

// ---------------- log_softmax in-place over rows of 64, one wave per row ----------------
__global__ __launch_bounds__(256) void logsoftmax_kernel(float* __restrict__ out, int M) {
    int n = blockIdx.x * 4 + (threadIdx.x >> 6);
    int lane = threadIdx.x & 63;
    if (n >= M) return;
    float v = out[(size_t)n * DOUT + lane];
    float m = v;
    #pragma unroll
    for (int off = 32; off >= 1; off >>= 1) m = fmaxf(m, __shfl_xor(m, off, 64));
    float e = expf(v - m);
    float ssum = e;
    #pragma unroll
    for (int off = 32; off >= 1; off >>= 1) ssum += __shfl_xor(ssum, off, 64);
    out[(size_t)n * DOUT + lane] = v - m - logf(ssum);
}

// ---------------- launch ----------------

extern "C" void kernel_launch(void* const* d_in, const int* in_sizes, int n_in,
                              void* d_out, int out_size, void* d_ws, size_t ws_size,
                              hipStream_t stream) {
    const float* x  = (const float*)d_in[0];
    const int*   ei = (const int*)d_in[1];
    const float* W1 = (const float*)d_in[2];
    const float* W2 = (const float*)d_in[3];
    float* out = (float*)d_out;

    const int N = in_sizes[0] / D;   // 20000
    const int E = in_sizes[1] / 2;   // 160000
    const int* src = ei;
    const int* dst = ei + E;

    size_t off = 0;
    auto alloc = [&](size_t bytes) -> void* {
        void* p = (char*)d_ws + off;
        off = (off + bytes + 255) & ~(size_t)255;
        return p;
    };
    int*   deg     = (int*)alloc(sizeof(int) * (size_t)N);
    int*   row_ptr = (int*)alloc(sizeof(int) * (size_t)(N + 1));
    int*   cursor  = (int*)alloc(sizeof(int) * (size_t)N);
    int*   col     = (int*)alloc(sizeof(int) * (size_t)E);
    float* h1      = (float*)alloc(sizeof(float) * (size_t)N * D);  // h1, later h3
    float* h2      = (float*)alloc(sizeof(float) * (size_t)N * D);

    hipMemsetAsync(deg, 0, sizeof(int) * (size_t)N, stream);
    degree_kernel<<<(E + 255) / 256, 256, 0, stream>>>(dst, deg, E);
    exscan_kernel<<<1, 1024, 0, stream>>>(deg, row_ptr, N);
    hipMemcpyAsync(cursor, row_ptr, sizeof(int) * (size_t)N,
                   hipMemcpyDeviceToDevice, stream);
    fill_kernel<<<(E + 255) / 256, 256, 0, stream>>>(src, dst, cursor, col, E);

    // h1 = segment_sum(x[src], dst)
    propagate_kernel<<<N, 128, 0, stream>>>(x, row_ptr, col, h1);
    // h2 = relu(h1 @ W1^T)
    dim3 g1(D / TN, (N + TM - 1) / TM);
    gemm_nt_kernel<<<g1, 256, 0, stream>>>(h1, W1, h2, N, D, D, 1);
    // h3 = segment_sum(h2[src], dst)  (into h1 buffer)
    propagate_kernel<<<N, 128, 0, stream>>>(h2, row_ptr, col, h1);
    // out = h3 @ W2^T
    dim3 g2(DOUT / TN, (N + TM - 1) / TM);
    gemm_nt_kernel<<<g2, 256, 0, stream>>>(h1, W2, out, N, DOUT, D, 0);
    // in-place log_softmax
    logsoftmax_kernel<<<(N + 3) / 4, 256, 0, stream>>>(out, N);
}

// Round 2
// 239.098 us; speedup vs baseline: 1.7501x; 1.7501x over previous
//
#include <hip/hip_runtime.h>

#define D 512
#define DOUT 64

typedef __bf16 bf16x8 __attribute__((ext_vector_type(8)));
typedef float floatx4 __attribute__((ext_vector_type(4)));

__device__ __forceinline__ void async_cp16(const void* g, void* lds) {
    __builtin_amdgcn_global_load_lds(
        (__attribute__((address_space(1))) void*)(void*)g,
        (__attribute__((address_space(3))) void*)lds, 16, 0, 0);
}

// ---------------- CSR build ----------------

__global__ void degree_kernel(const int* __restrict__ dst, int* __restrict__ deg, int nE) {
    int e = blockIdx.x * blockDim.x + threadIdx.x;
    if (e < nE) atomicAdd(&deg[dst[e]], 1);
}

__global__ __launch_bounds__(1024) void exscan_kernel(const int* __restrict__ deg,
                                                      int* __restrict__ rp, int n) {
    __shared__ int wtot[16];
    __shared__ int carry;
    int tid = threadIdx.x, lane = tid & 63, wid = tid >> 6;
    if (tid == 0) carry = 0;
    __syncthreads();
    for (int base = 0; base < n; base += 1024) {
        int i = base + tid;
        int v = (i < n) ? deg[i] : 0;
        int s = v;
        #pragma unroll
        for (int off = 1; off < 64; off <<= 1) {
            int t = __shfl_up(s, off, 64);
            if (lane >= off) s += t;
        }
        if (lane == 63) wtot[wid] = s;
        __syncthreads();
        if (wid == 0 && lane < 16) {
            int wv = wtot[lane];
            int ws_ = wv;
            #pragma unroll
            for (int off = 1; off < 16; off <<= 1) {
                int t = __shfl_up(ws_, off, 64);
                if (lane >= off) ws_ += t;
            }
            wtot[lane] = ws_ - wv;
        }
        __syncthreads();
        int excl = carry + wtot[wid] + (s - v);
        if (i < n) rp[i] = excl;
        __syncthreads();
        if (tid == 1023) carry = excl + v;
        __syncthreads();
    }
    if (tid == 0) rp[n] = carry;
}

__global__ void fill_kernel(const int* __restrict__ src, const int* __restrict__ dst,
                            int* __restrict__ cursor, int* __restrict__ col, int nE) {
    int e = blockIdx.x * blockDim.x + threadIdx.x;
    if (e < nE) {
        int d = dst[e];
        int p = atomicAdd(&cursor[d], 1);
        col[p] = src[e];
    }
}

// ---------------- f32 -> bf16 convert (8 elems/thread) ----------------
__global__ __launch_bounds__(256) void cvt_f32_bf16(const float* __restrict__ in,
        __bf16* __restrict__ out, int n8) {
    int i = blockIdx.x * 256 + threadIdx.x;
    if (i < n8) {
        const float4* p = (const float4*)in + (size_t)i * 2;
        float4 v0 = p[0], v1 = p[1];
        bf16x8 o;
        o[0] = (__bf16)v0.x; o[1] = (__bf16)v0.y; o[2] = (__bf16)v0.z; o[3] = (__bf16)v0.w;
        o[4] = (__bf16)v1.x; o[5] = (__bf16)v1.y; o[6] = (__bf16)v1.z; o[7] = (__bf16)v1.w;
        *((bf16x8*)out + i) = o;
    }
}

// ---------------- propagate (bf16 in, fp32 acc, bf16 out): wave per node ----------------
__global__ __launch_bounds__(256) void propagate_bf16(const __bf16* __restrict__ xin,
        const int* __restrict__ rp, const int* __restrict__ col,
        __bf16* __restrict__ out, int nN) {
    int n = blockIdx.x * 4 + (threadIdx.x >> 6);
    if (n >= nN) return;
    int lane = threadIdx.x & 63;
    int s0 = rp[n], s1 = rp[n + 1];
    float acc[8] = {};
    for (int e = s0; e < s1; ++e) {
        int s = col[e];
        bf16x8 v = *(const bf16x8*)(xin + (size_t)s * D + lane * 8);
        #pragma unroll
        for (int i = 0; i < 8; ++i) acc[i] += (float)v[i];
    }
    bf16x8 o;
    #pragma unroll
    for (int i = 0; i < 8; ++i) o[i] = (__bf16)acc[i];
    *(bf16x8*)(out + (size_t)n * D + lane * 8) = o;
}

// ---------------- bf16 MFMA NT GEMM: C[m,n] = sum_k A[m,k]*B[n,k] ----------------
// BM=128, BK=32. LDS planar layout: granule P = kquad*ROWS + row, 16B granules.
// Staged via global_load_lds (lane-contiguous LDS, arbitrary per-lane global addr).
template<int BN, int WR, int WC, bool RELU, bool OUTBF16>
__global__ __launch_bounds__(256) void gemm_mfma_nt(
        const __bf16* __restrict__ A, const __bf16* __restrict__ B,
        void* __restrict__ Cout, int M, int N, int K) {
    constexpr int BM = 128, BK = 32;
    constexpr int WM = BM / WR;       // wave tile rows
    constexpr int WN = BN / WC;       // wave tile cols
    constexpr int MI = WM / 16, NI = WN / 16;
    constexpr int CPA = BM / 64;      // 64-granule chunks per k-quad plane (A)
    constexpr int CPB = BN / 64;
    constexpr int CWA = CPA;          // chunks per wave (4 waves, 4 planes)
    constexpr int CWB = CPB;

    __shared__ __bf16 As[4 * BM * 8];
    __shared__ __bf16 Bs[4 * BN * 8];

    const int tid = threadIdx.x;
    const int w = tid >> 6, lane = tid & 63;
    const int wrow = w / WC, wcol = w % WC;
    const int m0 = blockIdx.y * BM, n0 = blockIdx.x * BN;
    const int quad = lane >> 4, l15 = lane & 15;

    floatx4 acc[MI][NI] = {};

    for (int k0 = 0; k0 < K; k0 += BK) {
        #pragma unroll
        for (int c = 0; c < CWA; ++c) {
            int ca = w * CWA + c;               // 0..4*CPA-1; P = ca*64 + lane
            int kq = ca / CPA;
            int row = m0 + (ca % CPA) * 64 + lane;
            if (row > M - 1) row = M - 1;
            async_cp16(A + (size_t)row * K + k0 + kq * 8, &As[(size_t)ca * 512]);
        }
        #pragma unroll
        for (int c = 0; c < CWB; ++c) {
            int cb = w * CWB + c;
            int kq = cb / CPB;
            int nn = n0 + (cb % CPB) * 64 + lane;
            async_cp16(B + (size_t)nn * K + k0 + kq * 8, &Bs[(size_t)cb * 512]);
        }
        __syncthreads();   // waits vmcnt(0): LDS staged

        bf16x8 af[MI], bf[NI];
        #pragma unroll
        for (int mi = 0; mi < MI; ++mi)
            af[mi] = *(const bf16x8*)&As[(size_t)(quad * BM + wrow * WM + mi * 16 + l15) * 8];
        #pragma unroll
        for (int nj = 0; nj < NI; ++nj)
            bf[nj] = *(const bf16x8*)&Bs[(size_t)(quad * BN + wcol * WN + nj * 16 + l15) * 8];
        #pragma unroll
        for (int mi = 0; mi < MI; ++mi)
            #pragma unroll
            for (int nj = 0; nj < NI; ++nj)
                acc[mi][nj] = __builtin_amdgcn_mfma_f32_16x16x32_bf16(
                    af[mi], bf[nj], acc[mi][nj], 0, 0, 0);
        __syncthreads();   // protect LDS before next stage
    }

    // C/D layout: col = lane&15, row = quad*4 + reg
    #pragma unroll
    for (int mi = 0; mi < MI; ++mi) {
        #pragma unroll
        for (int r = 0; r < 4; ++r) {
            int m = m0 + wrow * WM + mi * 16 + quad * 4 + r;
            if (m < M) {
                #pragma unroll
                for (int nj = 0; nj < NI; ++nj) {
                    int n = n0 + wcol * WN + nj * 16 + l15;
                    float v = acc[mi][nj][r];
                    if (RELU) v = fmaxf(v, 0.f);
                    if (OUTBF16) ((__bf16*)Cout)[(size_t)m * N + n] = (__bf16)v;
                    else         ((float*)Cout)[(size_t)m * N + n] = v;
                }
            }
        }
    }
}

// ---------------- log_softmax in-place, one wave per row of 64 ----------------
__global__ __launch_bounds__(256) void logsoftmax_kernel(float* __restrict__ out, int M) {
    int n = blockIdx.x * 4 + (threadIdx.x >> 6);
    int lane = threadIdx.x & 63;
    if (n >= M) return;
    float v = out[(size_t)n * DOUT + lane];
    float m = v;
    #pragma unroll
    for (int off = 32; off >= 1; off >>= 1) m = fmaxf(m, __shfl_xor(m, off, 64));
    float e = expf(v - m);
    float ssum = e;
    #pragma unroll
    for (int off = 32; off >= 1; off >>= 1) ssum += __shfl_xor(ssum, off, 64);
    out[(size_t)n * DOUT + lane] = v - m - logf(ssum);
}

// ---------------- launch ----------------

extern "C" void kernel_launch(void* const* d_in, const int* in_sizes, int n_in,
                              void* d_out, int out_size, void* d_ws, size_t ws_size,
                              hipStream_t stream) {
    const float* x  = (const float*)d_in[0];
    const int*   ei = (const int*)d_in[1];
    const float* W1 = (const float*)d_in[2];
    const float* W2 = (const float*)d_in[3];
    float* out = (float*)d_out;

    const int N = in_sizes[0] / D;   // 20000
    const int E = in_sizes[1] / 2;   // 160000
    const int* src = ei;
    const int* dst = ei + E;

    size_t off = 0;
    auto alloc = [&](size_t bytes) -> void* {
        void* p = (char*)d_ws + off;
        off = (off + bytes + 255) & ~(size_t)255;
        return p;
    };
    int*    deg     = (int*)alloc(sizeof(int) * (size_t)N);
    int*    row_ptr = (int*)alloc(sizeof(int) * (size_t)(N + 1));
    int*    cursor  = (int*)alloc(sizeof(int) * (size_t)N);
    int*    col     = (int*)alloc(sizeof(int) * (size_t)E);
    __bf16* w1b     = (__bf16*)alloc(sizeof(__bf16) * (size_t)D * D);
    __bf16* w2b     = (__bf16*)alloc(sizeof(__bf16) * (size_t)DOUT * D);
    __bf16* xb      = (__bf16*)alloc(sizeof(__bf16) * (size_t)N * D);  // x, later h3
    __bf16* hA      = (__bf16*)alloc(sizeof(__bf16) * (size_t)N * D);  // h1
    __bf16* hB      = (__bf16*)alloc(sizeof(__bf16) * (size_t)N * D);  // h2

    // CSR
    hipMemsetAsync(deg, 0, sizeof(int) * (size_t)N, stream);
    degree_kernel<<<(E + 255) / 256, 256, 0, stream>>>(dst, deg, E);
    exscan_kernel<<<1, 1024, 0, stream>>>(deg, row_ptr, N);
    hipMemcpyAsync(cursor, row_ptr, sizeof(int) * (size_t)N,
                   hipMemcpyDeviceToDevice, stream);
    fill_kernel<<<(E + 255) / 256, 256, 0, stream>>>(src, dst, cursor, col, E);

    // bf16 conversions
    cvt_f32_bf16<<<(N * D / 8 + 255) / 256, 256, 0, stream>>>(x, xb, N * D / 8);
    cvt_f32_bf16<<<(D * D / 8 + 255) / 256, 256, 0, stream>>>(W1, w1b, D * D / 8);
    cvt_f32_bf16<<<(DOUT * D / 8 + 255) / 256, 256, 0, stream>>>(W2, w2b, DOUT * D / 8);

    // h1 = segsum(x[src]) ; h2 = relu(h1 @ W1^T) ; h3 = segsum(h2[src]) ; out = h3 @ W2^T
    propagate_bf16<<<(N + 3) / 4, 256, 0, stream>>>(xb, row_ptr, col, hA, N);

    dim3 g1(D / 128, (N + 127) / 128);
    gemm_mfma_nt<128, 2, 2, true, true><<<g1, 256, 0, stream>>>(hA, w1b, hB, N, D, D);

    propagate_bf16<<<(N + 3) / 4, 256, 0, stream>>>(hB, row_ptr, col, xb, N);

    dim3 g2(1, (N + 127) / 128);
    gemm_mfma_nt<64, 4, 1, false, false><<<g2, 256, 0, stream>>>(xb, w2b, out, N, DOUT, D);

    logsoftmax_kernel<<<(N + 3) / 4, 256, 0, stream>>>(out, N);
}

// Round 3
// 224.054 us; speedup vs baseline: 1.8676x; 1.0671x over previous
//
#include <hip/hip_runtime.h>

#define D 512
#define DOUT 64

typedef __bf16 bf16x8 __attribute__((ext_vector_type(8)));
typedef float floatx4 __attribute__((ext_vector_type(4)));

__device__ __forceinline__ void async_cp16(const void* g, void* lds) {
    __builtin_amdgcn_global_load_lds(
        (__attribute__((address_space(1))) void*)(void*)g,
        (__attribute__((address_space(3))) void*)lds, 16, 0, 0);
}

// ---------------- CSR build ----------------

__global__ void degree_kernel(const int* __restrict__ dst, int* __restrict__ deg, int nE) {
    int e = blockIdx.x * blockDim.x + threadIdx.x;
    if (e < nE) atomicAdd(&deg[dst[e]], 1);
}

// single-block exclusive scan; writes rp[0..n] and cursor[0..n-1] (= rp copy)
__global__ __launch_bounds__(1024) void exscan_kernel(const int* __restrict__ deg,
                                                      int* __restrict__ rp,
                                                      int* __restrict__ cursor, int n) {
    __shared__ int wtot[16];
    __shared__ int carry;
    int tid = threadIdx.x, lane = tid & 63, wid = tid >> 6;
    if (tid == 0) carry = 0;
    __syncthreads();
    for (int base = 0; base < n; base += 1024) {
        int i = base + tid;
        int v = (i < n) ? deg[i] : 0;
        int s = v;
        #pragma unroll
        for (int off = 1; off < 64; off <<= 1) {
            int t = __shfl_up(s, off, 64);
            if (lane >= off) s += t;
        }
        if (lane == 63) wtot[wid] = s;
        __syncthreads();
        if (wid == 0 && lane < 16) {
            int wv = wtot[lane];
            int ws_ = wv;
            #pragma unroll
            for (int off = 1; off < 16; off <<= 1) {
                int t = __shfl_up(ws_, off, 64);
                if (lane >= off) ws_ += t;
            }
            wtot[lane] = ws_ - wv;
        }
        __syncthreads();
        int excl = carry + wtot[wid] + (s - v);
        if (i < n) { rp[i] = excl; cursor[i] = excl; }
        __syncthreads();
        if (tid == 1023) carry = excl + v;
        __syncthreads();
    }
    if (tid == 0) rp[n] = carry;
}

__global__ void fill_kernel(const int* __restrict__ src, const int* __restrict__ dst,
                            int* __restrict__ cursor, int* __restrict__ col, int nE) {
    int e = blockIdx.x * blockDim.x + threadIdx.x;
    if (e < nE) {
        int d = dst[e];
        int p = atomicAdd(&cursor[d], 1);
        col[p] = src[e];
    }
}

// ---------------- f32 -> bf16 convert (8 elems/thread) ----------------
__global__ __launch_bounds__(256) void cvt_f32_bf16(const float* __restrict__ in,
        __bf16* __restrict__ out, int n8) {
    int i = blockIdx.x * 256 + threadIdx.x;
    if (i < n8) {
        const float4* p = (const float4*)in + (size_t)i * 2;
        float4 v0 = p[0], v1 = p[1];
        bf16x8 o;
        o[0] = (__bf16)v0.x; o[1] = (__bf16)v0.y; o[2] = (__bf16)v0.z; o[3] = (__bf16)v0.w;
        o[4] = (__bf16)v1.x; o[5] = (__bf16)v1.y; o[6] = (__bf16)v1.z; o[7] = (__bf16)v1.w;
        *((bf16x8*)out + i) = o;
    }
}

// ---------------- propagate (bf16 in, fp32 acc, bf16 out): wave per node ----------------
__global__ __launch_bounds__(256) void propagate_bf16(const __bf16* __restrict__ xin,
        const int* __restrict__ rp, const int* __restrict__ col,
        __bf16* __restrict__ out, int nN) {
    int n = blockIdx.x * 4 + (threadIdx.x >> 6);
    if (n >= nN) return;
    int lane = threadIdx.x & 63;
    int s0 = rp[n], s1 = rp[n + 1];
    float acc0[8] = {}, acc1[8] = {};
    int e = s0;
    for (; e + 2 <= s1; e += 2) {
        int sa = col[e], sb = col[e + 1];
        bf16x8 va = *(const bf16x8*)(xin + (size_t)sa * D + lane * 8);
        bf16x8 vb = *(const bf16x8*)(xin + (size_t)sb * D + lane * 8);
        #pragma unroll
        for (int i = 0; i < 8; ++i) { acc0[i] += (float)va[i]; acc1[i] += (float)vb[i]; }
    }
    if (e < s1) {
        int sa = col[e];
        bf16x8 va = *(const bf16x8*)(xin + (size_t)sa * D + lane * 8);
        #pragma unroll
        for (int i = 0; i < 8; ++i) acc0[i] += (float)va[i];
    }
    bf16x8 o;
    #pragma unroll
    for (int i = 0; i < 8; ++i) o[i] = (__bf16)(acc0[i] + acc1[i]);
    *(bf16x8*)(out + (size_t)n * D + lane * 8) = o;
}

// ---------------- bf16 MFMA NT GEMM (bf16 out, optional relu) ----------------
// LDS planar layout: 16B granule P = kquad*BM + row, staged via global_load_lds.
template<int BM, int BN, int WR, int WC, bool RELU>
__global__ __launch_bounds__(256) void gemm_mfma_nt(
        const __bf16* __restrict__ A, const __bf16* __restrict__ B,
        __bf16* __restrict__ Cout, int M, int N, int K) {
    constexpr int BK = 32;
    constexpr int WM = BM / WR, WN = BN / WC;
    constexpr int MI = WM / 16, NI = WN / 16;
    constexpr int CPA = BM / 64, CPB = BN / 64;

    __shared__ __bf16 As[4 * BM * 8];
    __shared__ __bf16 Bs[4 * BN * 8];

    const int tid = threadIdx.x;
    const int w = tid >> 6, lane = tid & 63;
    const int wrow = w / WC, wcol = w % WC;
    const int m0 = blockIdx.y * BM, n0 = blockIdx.x * BN;
    const int quad = lane >> 4, l15 = lane & 15;

    floatx4 acc[MI][NI] = {};

    for (int k0 = 0; k0 < K; k0 += BK) {
        #pragma unroll
        for (int c = 0; c < CPA; ++c) {
            int ca = w * CPA + c;
            int kq = ca / CPA;
            int row = m0 + (ca % CPA) * 64 + lane;
            if (row > M - 1) row = M - 1;
            async_cp16(A + (size_t)row * K + k0 + kq * 8, &As[(size_t)ca * 512]);
        }
        #pragma unroll
        for (int c = 0; c < CPB; ++c) {
            int cb = w * CPB + c;
            int kq = cb / CPB;
            int nn = n0 + (cb % CPB) * 64 + lane;
            async_cp16(B + (size_t)nn * K + k0 + kq * 8, &Bs[(size_t)cb * 512]);
        }
        __syncthreads();

        bf16x8 af[MI], bfr[NI];
        #pragma unroll
        for (int mi = 0; mi < MI; ++mi)
            af[mi] = *(const bf16x8*)&As[(size_t)(quad * BM + wrow * WM + mi * 16 + l15) * 8];
        #pragma unroll
        for (int nj = 0; nj < NI; ++nj)
            bfr[nj] = *(const bf16x8*)&Bs[(size_t)(quad * BN + wcol * WN + nj * 16 + l15) * 8];
        #pragma unroll
        for (int mi = 0; mi < MI; ++mi)
            #pragma unroll
            for (int nj = 0; nj < NI; ++nj)
                acc[mi][nj] = __builtin_amdgcn_mfma_f32_16x16x32_bf16(
                    af[mi], bfr[nj], acc[mi][nj], 0, 0, 0);
        __syncthreads();
    }

    // C/D layout: col = l15, row = quad*4 + reg
    #pragma unroll
    for (int mi = 0; mi < MI; ++mi) {
        #pragma unroll
        for (int r = 0; r < 4; ++r) {
            int m = m0 + wrow * WM + mi * 16 + quad * 4 + r;
            if (m < M) {
                #pragma unroll
                for (int nj = 0; nj < NI; ++nj) {
                    int n = n0 + wcol * WN + nj * 16 + l15;
                    float v = acc[mi][nj][r];
                    if (RELU) v = fmaxf(v, 0.f);
                    Cout[(size_t)m * N + n] = (__bf16)v;
                }
            }
        }
    }
}

// ---------------- GEMM2 (N=64) + log_softmax fused, fp32 out ----------------
// BM=64, 4 waves; wave w owns rows [w*16, w*16+16) x all 64 cols. WM=16 -> MI=1, NI=4.
__global__ __launch_bounds__(256) void gemm2_lsm(
        const __bf16* __restrict__ A, const __bf16* __restrict__ B,
        float* __restrict__ Cout, int M, int K) {
    constexpr int BM = 64, BN = 64, BK = 32;
    __shared__ __bf16 As[4 * BM * 8];
    __shared__ __bf16 Bs[4 * BN * 8];

    const int tid = threadIdx.x;
    const int w = tid >> 6, lane = tid & 63;
    const int m0 = blockIdx.x * BM;
    const int quad = lane >> 4, l15 = lane & 15;

    floatx4 acc[4] = {};

    for (int k0 = 0; k0 < K; k0 += BK) {
        {   // A: wave w stages kquad w (64 rows x 16B)
            int row = m0 + lane;
            if (row > M - 1) row = M - 1;
            async_cp16(A + (size_t)row * K + k0 + w * 8, &As[(size_t)w * 512]);
            async_cp16(B + (size_t)lane * K + k0 + w * 8, &Bs[(size_t)w * 512]);
        }
        __syncthreads();
        bf16x8 af = *(const bf16x8*)&As[(size_t)(quad * BM + w * 16 + l15) * 8];
        #pragma unroll
        for (int nj = 0; nj < 4; ++nj) {
            bf16x8 bfr = *(const bf16x8*)&Bs[(size_t)(quad * BN + nj * 16 + l15) * 8];
            acc[nj] = __builtin_amdgcn_mfma_f32_16x16x32_bf16(af, bfr, acc[nj], 0, 0, 0);
        }
        __syncthreads();
    }

    // rows m = m0 + w*16 + quad*4 + r; cols nj*16 + l15
    #pragma unroll
    for (int r = 0; r < 4; ++r) {
        int m = m0 + w * 16 + quad * 4 + r;
        float v[4];
        #pragma unroll
        for (int nj = 0; nj < 4; ++nj) v[nj] = acc[nj][r];
        float mx = fmaxf(fmaxf(v[0], v[1]), fmaxf(v[2], v[3]));
        #pragma unroll
        for (int off = 8; off >= 1; off >>= 1) mx = fmaxf(mx, __shfl_xor(mx, off, 64));
        float s = expf(v[0] - mx) + expf(v[1] - mx) + expf(v[2] - mx) + expf(v[3] - mx);
        #pragma unroll
        for (int off = 8; off >= 1; off >>= 1) s += __shfl_xor(s, off, 64);
        float ls = mx + logf(s);
        if (m < M) {
            #pragma unroll
            for (int nj = 0; nj < 4; ++nj)
                Cout[(size_t)m * DOUT + nj * 16 + l15] = v[nj] - ls;
        }
    }
}

// ---------------- launch ----------------

extern "C" void kernel_launch(void* const* d_in, const int* in_sizes, int n_in,
                              void* d_out, int out_size, void* d_ws, size_t ws_size,
                              hipStream_t stream) {
    const float* x  = (const float*)d_in[0];
    const int*   ei = (const int*)d_in[1];
    const float* W1 = (const float*)d_in[2];
    const float* W2 = (const float*)d_in[3];
    float* out = (float*)d_out;

    const int N = in_sizes[0] / D;   // 20000
    const int E = in_sizes[1] / 2;   // 160000
    const int* src = ei;
    const int* dst = ei + E;

    size_t off = 0;
    auto alloc = [&](size_t bytes) -> void* {
        void* p = (char*)d_ws + off;
        off = (off + bytes + 255) & ~(size_t)255;
        return p;
    };
    int*    deg     = (int*)alloc(sizeof(int) * (size_t)N);
    int*    row_ptr = (int*)alloc(sizeof(int) * (size_t)(N + 1));
    int*    cursor  = (int*)alloc(sizeof(int) * (size_t)N);
    int*    col     = (int*)alloc(sizeof(int) * (size_t)E);
    __bf16* w1b     = (__bf16*)alloc(sizeof(__bf16) * (size_t)D * D);
    __bf16* w2b     = (__bf16*)alloc(sizeof(__bf16) * (size_t)DOUT * D);
    __bf16* xb      = (__bf16*)alloc(sizeof(__bf16) * (size_t)N * D);  // x, later h3
    __bf16* hA      = (__bf16*)alloc(sizeof(__bf16) * (size_t)N * D);  // h1
    __bf16* hB      = (__bf16*)alloc(sizeof(__bf16) * (size_t)N * D);  // h2

    // CSR
    hipMemsetAsync(deg, 0, sizeof(int) * (size_t)N, stream);
    degree_kernel<<<(E + 255) / 256, 256, 0, stream>>>(dst, deg, E);
    exscan_kernel<<<1, 1024, 0, stream>>>(deg, row_ptr, cursor, N);
    fill_kernel<<<(E + 255) / 256, 256, 0, stream>>>(src, dst, cursor, col, E);

    // bf16 conversions
    cvt_f32_bf16<<<(N * D / 8 + 255) / 256, 256, 0, stream>>>(x, xb, N * D / 8);
    cvt_f32_bf16<<<(D * D / 8 + 255) / 256, 256, 0, stream>>>(W1, w1b, D * D / 8);
    cvt_f32_bf16<<<(DOUT * D / 8 + 255) / 256, 256, 0, stream>>>(W2, w2b, DOUT * D / 8);

    // h1 = segsum(x[src]) ; h2 = relu(h1 @ W1^T) ; h3 = segsum(h2[src]) ; out = lsm(h3 @ W2^T)
    propagate_bf16<<<(N + 3) / 4, 256, 0, stream>>>(xb, row_ptr, col, hA, N);

    dim3 g1(D / 128, (N + 127) / 128);
    gemm_mfma_nt<128, 128, 2, 2, true><<<g1, 256, 0, stream>>>(hA, w1b, hB, N, D, D);

    propagate_bf16<<<(N + 3) / 4, 256, 0, stream>>>(hB, row_ptr, col, xb, N);

    gemm2_lsm<<<(N + 63) / 64, 256, 0, stream>>>(xb, w2b, out, N, D);
}

// Round 4
// 201.754 us; speedup vs baseline: 2.0740x; 1.1105x over previous
//
#include <hip/hip_runtime.h>

#define D 512
#define DOUT 64

typedef __bf16 bf16x8 __attribute__((ext_vector_type(8)));
typedef float floatx4 __attribute__((ext_vector_type(4)));

__device__ __forceinline__ void async_cp16(const void* g, void* lds) {
    __builtin_amdgcn_global_load_lds(
        (__attribute__((address_space(1))) void*)(void*)g,
        (__attribute__((address_space(3))) void*)lds, 16, 0, 0);
}

// ---- fused: degree atomics + 3 f32->bf16 conversions, partitioned by blockIdx ----
__global__ __launch_bounds__(256) void misc_kernel(
        const int* __restrict__ dst, int* __restrict__ deg, int nE, int degBlocks,
        const float* __restrict__ x, __bf16* __restrict__ xb, int xN8,
        const float* __restrict__ W1, __bf16* __restrict__ w1b, int w1N8,
        const float* __restrict__ W2, __bf16* __restrict__ w2b, int w2N8) {
    int b = blockIdx.x;
    if (b < degBlocks) {
        int e = b * 256 + threadIdx.x;
        if (e < nE) atomicAdd(&deg[dst[e]], 1);
        return;
    }
    b -= degBlocks;
    int xBlocks = (xN8 + 255) >> 8;
    int w1Blocks = (w1N8 + 255) >> 8;
    const float* in; __bf16* outp; int n8;
    if (b < xBlocks) { in = x; outp = xb; n8 = xN8; }
    else if (b < xBlocks + w1Blocks) { b -= xBlocks; in = W1; outp = w1b; n8 = w1N8; }
    else { b -= xBlocks + w1Blocks; in = W2; outp = w2b; n8 = w2N8; }
    int i = b * 256 + threadIdx.x;
    if (i < n8) {
        const float4* p = (const float4*)in + (size_t)i * 2;
        float4 v0 = p[0], v1 = p[1];
        bf16x8 o;
        o[0] = (__bf16)v0.x; o[1] = (__bf16)v0.y; o[2] = (__bf16)v0.z; o[3] = (__bf16)v0.w;
        o[4] = (__bf16)v1.x; o[5] = (__bf16)v1.y; o[6] = (__bf16)v1.z; o[7] = (__bf16)v1.w;
        *((bf16x8*)outp + i) = o;
    }
}

// ---- single-block exclusive scan, 4 elems/thread; writes rp[0..n] and cursor ----
__global__ __launch_bounds__(1024) void exscan_kernel(const int* __restrict__ deg,
                                                      int* __restrict__ rp,
                                                      int* __restrict__ cursor, int n) {
    __shared__ int wtot[16];
    __shared__ int carry;
    int tid = threadIdx.x, lane = tid & 63, wid = tid >> 6;
    if (tid == 0) carry = 0;
    __syncthreads();
    for (int base = 0; base < n; base += 4096) {
        int i4 = base + tid * 4;
        int4 v = make_int4(0, 0, 0, 0);
        if (i4 + 3 < n) v = *(const int4*)(deg + i4);
        else {
            if (i4 + 0 < n) v.x = deg[i4 + 0];
            if (i4 + 1 < n) v.y = deg[i4 + 1];
            if (i4 + 2 < n) v.z = deg[i4 + 2];
            if (i4 + 3 < n) v.w = deg[i4 + 3];
        }
        int tsum = v.x + v.y + v.z + v.w;
        int s = tsum;
        #pragma unroll
        for (int off = 1; off < 64; off <<= 1) {
            int t = __shfl_up(s, off, 64);
            if (lane >= off) s += t;
        }
        if (lane == 63) wtot[wid] = s;
        __syncthreads();
        if (wid == 0 && lane < 16) {
            int wv = wtot[lane];
            int ws_ = wv;
            #pragma unroll
            for (int off = 1; off < 16; off <<= 1) {
                int t = __shfl_up(ws_, off, 64);
                if (lane >= off) ws_ += t;
            }
            wtot[lane] = ws_ - wv;
        }
        __syncthreads();
        int excl = carry + wtot[wid] + (s - tsum);
        int4 o;
        o.x = excl; o.y = o.x + v.x; o.z = o.y + v.y; o.w = o.z + v.z;
        if (i4 + 3 < n) {
            *(int4*)(rp + i4) = o;
            *(int4*)(cursor + i4) = o;
        } else {
            if (i4 + 0 < n) { rp[i4 + 0] = o.x; cursor[i4 + 0] = o.x; }
            if (i4 + 1 < n) { rp[i4 + 1] = o.y; cursor[i4 + 1] = o.y; }
            if (i4 + 2 < n) { rp[i4 + 2] = o.z; cursor[i4 + 2] = o.z; }
            if (i4 + 3 < n) { rp[i4 + 3] = o.w; cursor[i4 + 3] = o.w; }
        }
        __syncthreads();
        if (tid == 1023) carry = o.w + v.w;
        __syncthreads();
    }
    if (tid == 0) rp[n] = carry;
}

__global__ void fill_kernel(const int* __restrict__ src, const int* __restrict__ dst,
                            int* __restrict__ cursor, int* __restrict__ col, int nE) {
    int e = blockIdx.x * blockDim.x + threadIdx.x;
    if (e < nE) {
        int d = dst[e];
        int p = atomicAdd(&cursor[d], 1);
        col[p] = src[e];
    }
}

// ---- propagate (bf16 in, fp32 acc, bf16 out): wave per node, 4 gathers in flight ----
__global__ __launch_bounds__(256) void propagate_bf16(const __bf16* __restrict__ xin,
        const int* __restrict__ rp, const int* __restrict__ col,
        __bf16* __restrict__ out, int nN) {
    int n = blockIdx.x * 4 + (threadIdx.x >> 6);
    if (n >= nN) return;
    int lane = threadIdx.x & 63;
    int s0 = rp[n], s1 = rp[n + 1];
    float acc0[8] = {}, acc1[8] = {};
    int e = s0;
    for (; e + 4 <= s1; e += 4) {
        int sa = col[e], sb = col[e + 1], sc = col[e + 2], sd = col[e + 3];
        bf16x8 va = *(const bf16x8*)(xin + (size_t)sa * D + lane * 8);
        bf16x8 vb = *(const bf16x8*)(xin + (size_t)sb * D + lane * 8);
        bf16x8 vc = *(const bf16x8*)(xin + (size_t)sc * D + lane * 8);
        bf16x8 vd = *(const bf16x8*)(xin + (size_t)sd * D + lane * 8);
        #pragma unroll
        for (int i = 0; i < 8; ++i) {
            acc0[i] += (float)va[i] + (float)vc[i];
            acc1[i] += (float)vb[i] + (float)vd[i];
        }
    }
    for (; e < s1; ++e) {
        int sa = col[e];
        bf16x8 va = *(const bf16x8*)(xin + (size_t)sa * D + lane * 8);
        #pragma unroll
        for (int i = 0; i < 8; ++i) acc0[i] += (float)va[i];
    }
    bf16x8 o;
    #pragma unroll
    for (int i = 0; i < 8; ++i) o[i] = (__bf16)(acc0[i] + acc1[i]);
    *(bf16x8*)(out + (size_t)n * D + lane * 8) = o;
}

// ---- bf16 MFMA NT GEMM (bf16 out, relu) — unchanged m97-style ----
template<int BM, int BN, int WR, int WC, bool RELU>
__global__ __launch_bounds__(256) void gemm_mfma_nt(
        const __bf16* __restrict__ A, const __bf16* __restrict__ B,
        __bf16* __restrict__ Cout, int M, int N, int K) {
    constexpr int BK = 32;
    constexpr int WM = BM / WR, WN = BN / WC;
    constexpr int MI = WM / 16, NI = WN / 16;
    constexpr int CPA = BM / 64, CPB = BN / 64;

    __shared__ __bf16 As[4 * BM * 8];
    __shared__ __bf16 Bs[4 * BN * 8];

    const int tid = threadIdx.x;
    const int w = tid >> 6, lane = tid & 63;
    const int wrow = w / WC, wcol = w % WC;
    const int m0 = blockIdx.y * BM, n0 = blockIdx.x * BN;
    const int quad = lane >> 4, l15 = lane & 15;

    floatx4 acc[MI][NI] = {};

    for (int k0 = 0; k0 < K; k0 += BK) {
        #pragma unroll
        for (int c = 0; c < CPA; ++c) {
            int ca = w * CPA + c;
            int kq = ca / CPA;
            int row = m0 + (ca % CPA) * 64 + lane;
            if (row > M - 1) row = M - 1;
            async_cp16(A + (size_t)row * K + k0 + kq * 8, &As[(size_t)ca * 512]);
        }
        #pragma unroll
        for (int c = 0; c < CPB; ++c) {
            int cb = w * CPB + c;
            int kq = cb / CPB;
            int nn = n0 + (cb % CPB) * 64 + lane;
            async_cp16(B + (size_t)nn * K + k0 + kq * 8, &Bs[(size_t)cb * 512]);
        }
        __syncthreads();

        bf16x8 af[MI], bfr[NI];
        #pragma unroll
        for (int mi = 0; mi < MI; ++mi)
            af[mi] = *(const bf16x8*)&As[(size_t)(quad * BM + wrow * WM + mi * 16 + l15) * 8];
        #pragma unroll
        for (int nj = 0; nj < NI; ++nj)
            bfr[nj] = *(const bf16x8*)&Bs[(size_t)(quad * BN + wcol * WN + nj * 16 + l15) * 8];
        #pragma unroll
        for (int mi = 0; mi < MI; ++mi)
            #pragma unroll
            for (int nj = 0; nj < NI; ++nj)
                acc[mi][nj] = __builtin_amdgcn_mfma_f32_16x16x32_bf16(
                    af[mi], bfr[nj], acc[mi][nj], 0, 0, 0);
        __syncthreads();
    }

    #pragma unroll
    for (int mi = 0; mi < MI; ++mi) {
        #pragma unroll
        for (int r = 0; r < 4; ++r) {
            int m = m0 + wrow * WM + mi * 16 + quad * 4 + r;
            if (m < M) {
                #pragma unroll
                for (int nj = 0; nj < NI; ++nj) {
                    int n = n0 + wcol * WN + nj * 16 + l15;
                    float v = acc[mi][nj][r];
                    if (RELU) v = fmaxf(v, 0.f);
                    Cout[(size_t)m * N + n] = (__bf16)v;
                }
            }
        }
    }
}

// ---- fused propagate2 + GEMM2 (N=64) + log_softmax, fp32 out ----
// BM=32 nodes/block, 4 waves (WR=2,WC=2). Gather h3 rows straight into LDS A-tile
// (swizzled granules), then K-loop streams W2 chunks, lsm via 2-barrier LDS partials.
__global__ __launch_bounds__(256) void prop_gemm2_lsm(
        const __bf16* __restrict__ h2, const int* __restrict__ rp,
        const int* __restrict__ col, const __bf16* __restrict__ B,
        float* __restrict__ out, int nN) {
    __shared__ __bf16 As[32 * 512];    // 32KB: granule P = r*64 + ((g+r)&63)
    __shared__ __bf16 Bs[4 * 64 * 8];  // 4KB chunk: granule P = kq*64 + n
    __shared__ float pm[64], ps[64];

    const int tid = threadIdx.x;
    const int w = tid >> 6, lane = tid & 63;
    const int quad = lane >> 4, l15 = lane & 15;
    const int wrow = w >> 1, wcol = w & 1;
    const int m0 = blockIdx.x * 32;

    // --- gather phase: wave w does local rows w, w+4, ..., w+28 ---
    for (int r = w; r < 32; r += 4) {
        int n = m0 + r;
        float acc0[8] = {}, acc1[8] = {};
        if (n < nN) {
            int s0 = rp[n], s1 = rp[n + 1];
            int e = s0;
            for (; e + 4 <= s1; e += 4) {
                int sa = col[e], sb = col[e + 1], sc = col[e + 2], sd = col[e + 3];
                bf16x8 va = *(const bf16x8*)(h2 + (size_t)sa * D + lane * 8);
                bf16x8 vb = *(const bf16x8*)(h2 + (size_t)sb * D + lane * 8);
                bf16x8 vc = *(const bf16x8*)(h2 + (size_t)sc * D + lane * 8);
                bf16x8 vd = *(const bf16x8*)(h2 + (size_t)sd * D + lane * 8);
                #pragma unroll
                for (int i = 0; i < 8; ++i) {
                    acc0[i] += (float)va[i] + (float)vc[i];
                    acc1[i] += (float)vb[i] + (float)vd[i];
                }
            }
            for (; e < s1; ++e) {
                int sa = col[e];
                bf16x8 va = *(const bf16x8*)(h2 + (size_t)sa * D + lane * 8);
                #pragma unroll
                for (int i = 0; i < 8; ++i) acc0[i] += (float)va[i];
            }
        }
        bf16x8 o;
        #pragma unroll
        for (int i = 0; i < 8; ++i) o[i] = (__bf16)(acc0[i] + acc1[i]);
        int P = r * 64 + ((lane + r) & 63);
        *(bf16x8*)&As[(size_t)P * 8] = o;
    }
    __syncthreads();

    // --- K-loop ---
    floatx4 acc[2] = {};
    for (int k0 = 0; k0 < D; k0 += 32) {
        async_cp16(B + (size_t)lane * D + k0 + w * 8, &Bs[(size_t)w * 512]);
        __syncthreads();
        int g = (k0 >> 3) + quad;
        int row = wrow * 16 + l15;
        bf16x8 af = *(const bf16x8*)&As[(size_t)(row * 64 + ((g + row) & 63)) * 8];
        #pragma unroll
        for (int nj = 0; nj < 2; ++nj) {
            bf16x8 bfr = *(const bf16x8*)&Bs[(size_t)(quad * 64 + wcol * 32 + nj * 16 + l15) * 8];
            acc[nj] = __builtin_amdgcn_mfma_f32_16x16x32_bf16(af, bfr, acc[nj], 0, 0, 0);
        }
        __syncthreads();
    }

    // --- log_softmax: rows split across wcol pairs; 2-barrier LDS combine ---
    float v0a[4], v1a[4], mx[4], sm[4];
    #pragma unroll
    for (int r = 0; r < 4; ++r) {
        v0a[r] = acc[0][r]; v1a[r] = acc[1][r];
        float m = fmaxf(v0a[r], v1a[r]);
        #pragma unroll
        for (int off = 8; off >= 1; off >>= 1) m = fmaxf(m, __shfl_xor(m, off, 64));
        mx[r] = m;
        if (l15 == 0) pm[wrow * 32 + wcol * 16 + quad * 4 + r] = m;
    }
    __syncthreads();
    #pragma unroll
    for (int r = 0; r < 4; ++r) {
        mx[r] = fmaxf(mx[r], pm[wrow * 32 + (1 - wcol) * 16 + quad * 4 + r]);
        float s = expf(v0a[r] - mx[r]) + expf(v1a[r] - mx[r]);
        #pragma unroll
        for (int off = 8; off >= 1; off >>= 1) s += __shfl_xor(s, off, 64);
        sm[r] = s;
        if (l15 == 0) ps[wrow * 32 + wcol * 16 + quad * 4 + r] = s;
    }
    __syncthreads();
    #pragma unroll
    for (int r = 0; r < 4; ++r) {
        float st = sm[r] + ps[wrow * 32 + (1 - wcol) * 16 + quad * 4 + r];
        float ls = mx[r] + logf(st);
        int m = m0 + wrow * 16 + quad * 4 + r;
        if (m < nN) {
            out[(size_t)m * DOUT + wcol * 32 + l15]      = v0a[r] - ls;
            out[(size_t)m * DOUT + wcol * 32 + 16 + l15] = v1a[r] - ls;
        }
    }
}

// ---------------- launch ----------------

extern "C" void kernel_launch(void* const* d_in, const int* in_sizes, int n_in,
                              void* d_out, int out_size, void* d_ws, size_t ws_size,
                              hipStream_t stream) {
    const float* x  = (const float*)d_in[0];
    const int*   ei = (const int*)d_in[1];
    const float* W1 = (const float*)d_in[2];
    const float* W2 = (const float*)d_in[3];
    float* out = (float*)d_out;

    const int N = in_sizes[0] / D;   // 20000
    const int E = in_sizes[1] / 2;   // 160000
    const int* src = ei;
    const int* dst = ei + E;

    size_t off = 0;
    auto alloc = [&](size_t bytes) -> void* {
        void* p = (char*)d_ws + off;
        off = (off + bytes + 255) & ~(size_t)255;
        return p;
    };
    int*    deg     = (int*)alloc(sizeof(int) * (size_t)N);
    int*    row_ptr = (int*)alloc(sizeof(int) * (size_t)(N + 1));
    int*    cursor  = (int*)alloc(sizeof(int) * (size_t)N);
    int*    col     = (int*)alloc(sizeof(int) * (size_t)E);
    __bf16* w1b     = (__bf16*)alloc(sizeof(__bf16) * (size_t)D * D);
    __bf16* w2b     = (__bf16*)alloc(sizeof(__bf16) * (size_t)DOUT * D);
    __bf16* xb      = (__bf16*)alloc(sizeof(__bf16) * (size_t)N * D);
    __bf16* hA      = (__bf16*)alloc(sizeof(__bf16) * (size_t)N * D);  // h1
    __bf16* hB      = (__bf16*)alloc(sizeof(__bf16) * (size_t)N * D);  // h2

    const int degBlocks = (E + 255) / 256;
    const int xN8 = N * D / 8, w1N8 = D * D / 8, w2N8 = DOUT * D / 8;
    const int cvtBlocks = (xN8 + 255) / 256 + (w1N8 + 255) / 256 + (w2N8 + 255) / 256;

    hipMemsetAsync(deg, 0, sizeof(int) * (size_t)N, stream);
    misc_kernel<<<degBlocks + cvtBlocks, 256, 0, stream>>>(
        dst, deg, E, degBlocks, x, xb, xN8, W1, w1b, w1N8, W2, w2b, w2N8);
    exscan_kernel<<<1, 1024, 0, stream>>>(deg, row_ptr, cursor, N);
    fill_kernel<<<(E + 255) / 256, 256, 0, stream>>>(src, dst, cursor, col, E);

    // h1 = segsum(x[src])
    propagate_bf16<<<(N + 3) / 4, 256, 0, stream>>>(xb, row_ptr, col, hA, N);
    // h2 = relu(h1 @ W1^T)
    dim3 g1(D / 128, (N + 127) / 128);
    gemm_mfma_nt<128, 128, 2, 2, true><<<g1, 256, 0, stream>>>(hA, w1b, hB, N, D, D);
    // out = lsm(segsum(h2[src]) @ W2^T), fused
    prop_gemm2_lsm<<<(N + 31) / 32, 256, 0, stream>>>(hB, row_ptr, col, w2b, out, N);
}

// Round 5
// 188.545 us; speedup vs baseline: 2.2193x; 1.0701x over previous
//
#include <hip/hip_runtime.h>

#define D 512
#define DOUT 64

typedef __bf16 bf16x8 __attribute__((ext_vector_type(8)));
typedef float floatx4 __attribute__((ext_vector_type(4)));

__device__ __forceinline__ void async_cp16(const void* g, void* lds) {
    __builtin_amdgcn_global_load_lds(
        (__attribute__((address_space(1))) void*)(void*)g,
        (__attribute__((address_space(3))) void*)lds, 16, 0, 0);
}

// ---- fused: degree atomics + 3 f32->bf16 conversions, partitioned by blockIdx ----
__global__ __launch_bounds__(256) void misc_kernel(
        const int* __restrict__ dst, int* __restrict__ deg, int nE, int degBlocks,
        const float* __restrict__ x, __bf16* __restrict__ xb, int xN8,
        const float* __restrict__ W1, __bf16* __restrict__ w1b, int w1N8,
        const float* __restrict__ W2, __bf16* __restrict__ w2b, int w2N8) {
    int b = blockIdx.x;
    if (b < degBlocks) {
        int e = b * 256 + threadIdx.x;
        if (e < nE) atomicAdd(&deg[dst[e]], 1);
        return;
    }
    b -= degBlocks;
    int xBlocks = (xN8 + 255) >> 8;
    int w1Blocks = (w1N8 + 255) >> 8;
    const float* in; __bf16* outp; int n8;
    if (b < xBlocks) { in = x; outp = xb; n8 = xN8; }
    else if (b < xBlocks + w1Blocks) { b -= xBlocks; in = W1; outp = w1b; n8 = w1N8; }
    else { b -= xBlocks + w1Blocks; in = W2; outp = w2b; n8 = w2N8; }
    int i = b * 256 + threadIdx.x;
    if (i < n8) {
        const float4* p = (const float4*)in + (size_t)i * 2;
        float4 v0 = p[0], v1 = p[1];
        bf16x8 o;
        o[0] = (__bf16)v0.x; o[1] = (__bf16)v0.y; o[2] = (__bf16)v0.z; o[3] = (__bf16)v0.w;
        o[4] = (__bf16)v1.x; o[5] = (__bf16)v1.y; o[6] = (__bf16)v1.z; o[7] = (__bf16)v1.w;
        *((bf16x8*)outp + i) = o;
    }
}

// ---- single-block exclusive scan, 4 elems/thread; writes rp[0..n] and cursor ----
__global__ __launch_bounds__(1024) void exscan_kernel(const int* __restrict__ deg,
                                                      int* __restrict__ rp,
                                                      int* __restrict__ cursor, int n) {
    __shared__ int wtot[16];
    __shared__ int carry;
    int tid = threadIdx.x, lane = tid & 63, wid = tid >> 6;
    if (tid == 0) carry = 0;
    __syncthreads();
    for (int base = 0; base < n; base += 4096) {
        int i4 = base + tid * 4;
        int4 v = make_int4(0, 0, 0, 0);
        if (i4 + 3 < n) v = *(const int4*)(deg + i4);
        else {
            if (i4 + 0 < n) v.x = deg[i4 + 0];
            if (i4 + 1 < n) v.y = deg[i4 + 1];
            if (i4 + 2 < n) v.z = deg[i4 + 2];
            if (i4 + 3 < n) v.w = deg[i4 + 3];
        }
        int tsum = v.x + v.y + v.z + v.w;
        int s = tsum;
        #pragma unroll
        for (int off = 1; off < 64; off <<= 1) {
            int t = __shfl_up(s, off, 64);
            if (lane >= off) s += t;
        }
        if (lane == 63) wtot[wid] = s;
        __syncthreads();
        if (wid == 0 && lane < 16) {
            int wv = wtot[lane];
            int ws_ = wv;
            #pragma unroll
            for (int off = 1; off < 16; off <<= 1) {
                int t = __shfl_up(ws_, off, 64);
                if (lane >= off) ws_ += t;
            }
            wtot[lane] = ws_ - wv;
        }
        __syncthreads();
        int excl = carry + wtot[wid] + (s - tsum);
        int4 o;
        o.x = excl; o.y = o.x + v.x; o.z = o.y + v.y; o.w = o.z + v.z;
        if (i4 + 3 < n) {
            *(int4*)(rp + i4) = o;
            *(int4*)(cursor + i4) = o;
        } else {
            if (i4 + 0 < n) { rp[i4 + 0] = o.x; cursor[i4 + 0] = o.x; }
            if (i4 + 1 < n) { rp[i4 + 1] = o.y; cursor[i4 + 1] = o.y; }
            if (i4 + 2 < n) { rp[i4 + 2] = o.z; cursor[i4 + 2] = o.z; }
            if (i4 + 3 < n) { rp[i4 + 3] = o.w; cursor[i4 + 3] = o.w; }
        }
        __syncthreads();
        if (tid == 1023) carry = o.w + v.w;
        __syncthreads();
    }
    if (tid == 0) rp[n] = carry;
}

__global__ void fill_kernel(const int* __restrict__ src, const int* __restrict__ dst,
                            int* __restrict__ cursor, int* __restrict__ col, int nE) {
    int e = blockIdx.x * blockDim.x + threadIdx.x;
    if (e < nE) {
        int d = dst[e];
        int p = atomicAdd(&cursor[d], 1);
        col[p] = src[e];
    }
}

// ---- propagate 512-wide (bf16 in, fp32 acc, bf16 out, optional relu): wave/node ----
template<bool RELU>
__global__ __launch_bounds__(256) void propagate_bf16(const __bf16* __restrict__ xin,
        const int* __restrict__ rp, const int* __restrict__ col,
        __bf16* __restrict__ out, int nN) {
    int n = blockIdx.x * 4 + (threadIdx.x >> 6);
    if (n >= nN) return;
    int lane = threadIdx.x & 63;
    int s0 = rp[n], s1 = rp[n + 1];
    float acc0[8] = {}, acc1[8] = {};
    int e = s0;
    for (; e + 4 <= s1; e += 4) {
        int sa = col[e], sb = col[e + 1], sc = col[e + 2], sd = col[e + 3];
        bf16x8 va = *(const bf16x8*)(xin + (size_t)sa * D + lane * 8);
        bf16x8 vb = *(const bf16x8*)(xin + (size_t)sb * D + lane * 8);
        bf16x8 vc = *(const bf16x8*)(xin + (size_t)sc * D + lane * 8);
        bf16x8 vd = *(const bf16x8*)(xin + (size_t)sd * D + lane * 8);
        #pragma unroll
        for (int i = 0; i < 8; ++i) {
            acc0[i] += (float)va[i] + (float)vc[i];
            acc1[i] += (float)vb[i] + (float)vd[i];
        }
    }
    for (; e < s1; ++e) {
        int sa = col[e];
        bf16x8 va = *(const bf16x8*)(xin + (size_t)sa * D + lane * 8);
        #pragma unroll
        for (int i = 0; i < 8; ++i) acc0[i] += (float)va[i];
    }
    bf16x8 o;
    #pragma unroll
    for (int i = 0; i < 8; ++i) {
        float v = acc0[i] + acc1[i];
        if (RELU) v = fmaxf(v, 0.f);
        o[i] = (__bf16)v;
    }
    *(bf16x8*)(out + (size_t)n * D + lane * 8) = o;
}

// ---- bf16 MFMA NT GEMM (bf16 out, optional relu) — m97-style ----
template<int BM, int BN, int WR, int WC, bool RELU>
__global__ __launch_bounds__(256) void gemm_mfma_nt(
        const __bf16* __restrict__ A, const __bf16* __restrict__ B,
        __bf16* __restrict__ Cout, int M, int N, int K) {
    constexpr int BK = 32;
    constexpr int WM = BM / WR, WN = BN / WC;
    constexpr int MI = WM / 16, NI = WN / 16;
    constexpr int CPA = BM / 64, CPB = BN / 64;

    __shared__ __bf16 As[4 * BM * 8];
    __shared__ __bf16 Bs[4 * BN * 8];

    const int tid = threadIdx.x;
    const int w = tid >> 6, lane = tid & 63;
    const int wrow = w / WC, wcol = w % WC;
    const int m0 = blockIdx.y * BM, n0 = blockIdx.x * BN;
    const int quad = lane >> 4, l15 = lane & 15;

    floatx4 acc[MI][NI] = {};

    for (int k0 = 0; k0 < K; k0 += BK) {
        #pragma unroll
        for (int c = 0; c < CPA; ++c) {
            int ca = w * CPA + c;
            int kq = ca / CPA;
            int row = m0 + (ca % CPA) * 64 + lane;
            if (row > M - 1) row = M - 1;
            async_cp16(A + (size_t)row * K + k0 + kq * 8, &As[(size_t)ca * 512]);
        }
        #pragma unroll
        for (int c = 0; c < CPB; ++c) {
            int cb = w * CPB + c;
            int kq = cb / CPB;
            int nn = n0 + (cb % CPB) * 64 + lane;
            async_cp16(B + (size_t)nn * K + k0 + kq * 8, &Bs[(size_t)cb * 512]);
        }
        __syncthreads();

        bf16x8 af[MI], bfr[NI];
        #pragma unroll
        for (int mi = 0; mi < MI; ++mi)
            af[mi] = *(const bf16x8*)&As[(size_t)(quad * BM + wrow * WM + mi * 16 + l15) * 8];
        #pragma unroll
        for (int nj = 0; nj < NI; ++nj)
            bfr[nj] = *(const bf16x8*)&Bs[(size_t)(quad * BN + wcol * WN + nj * 16 + l15) * 8];
        #pragma unroll
        for (int mi = 0; mi < MI; ++mi)
            #pragma unroll
            for (int nj = 0; nj < NI; ++nj)
                acc[mi][nj] = __builtin_amdgcn_mfma_f32_16x16x32_bf16(
                    af[mi], bfr[nj], acc[mi][nj], 0, 0, 0);
        __syncthreads();
    }

    #pragma unroll
    for (int mi = 0; mi < MI; ++mi) {
        #pragma unroll
        for (int r = 0; r < 4; ++r) {
            int m = m0 + wrow * WM + mi * 16 + quad * 4 + r;
            if (m < M) {
                #pragma unroll
                for (int nj = 0; nj < NI; ++nj) {
                    int n = n0 + wcol * WN + nj * 16 + l15;
                    float v = acc[mi][nj][r];
                    if (RELU) v = fmaxf(v, 0.f);
                    Cout[(size_t)m * N + n] = (__bf16)v;
                }
            }
        }
    }
}

// ---- propagate 64-wide + log_softmax fused: wave per node, lane = output col ----
__global__ __launch_bounds__(256) void prop2_lsm(const __bf16* __restrict__ u,
        const int* __restrict__ rp, const int* __restrict__ col,
        float* __restrict__ out, int nN) {
    int n = blockIdx.x * 4 + (threadIdx.x >> 6);
    if (n >= nN) return;
    int lane = threadIdx.x & 63;
    int s0 = rp[n], s1 = rp[n + 1];
    float a0 = 0.f, a1 = 0.f, a2 = 0.f, a3 = 0.f;
    int e = s0;
    for (; e + 4 <= s1; e += 4) {
        int sa = col[e], sb = col[e + 1], sc = col[e + 2], sd = col[e + 3];
        a0 += (float)u[(size_t)sa * DOUT + lane];
        a1 += (float)u[(size_t)sb * DOUT + lane];
        a2 += (float)u[(size_t)sc * DOUT + lane];
        a3 += (float)u[(size_t)sd * DOUT + lane];
    }
    for (; e < s1; ++e) a0 += (float)u[(size_t)col[e] * DOUT + lane];
    float v = (a0 + a2) + (a1 + a3);
    float mx = v;
    #pragma unroll
    for (int off = 32; off >= 1; off >>= 1) mx = fmaxf(mx, __shfl_xor(mx, off, 64));
    float s = expf(v - mx);
    #pragma unroll
    for (int off = 32; off >= 1; off >>= 1) s += __shfl_xor(s, off, 64);
    out[(size_t)n * DOUT + lane] = v - mx - logf(s);
}

// ---------------- launch ----------------

extern "C" void kernel_launch(void* const* d_in, const int* in_sizes, int n_in,
                              void* d_out, int out_size, void* d_ws, size_t ws_size,
                              hipStream_t stream) {
    const float* x  = (const float*)d_in[0];
    const int*   ei = (const int*)d_in[1];
    const float* W1 = (const float*)d_in[2];
    const float* W2 = (const float*)d_in[3];
    float* out = (float*)d_out;

    const int N = in_sizes[0] / D;   // 20000
    const int E = in_sizes[1] / 2;   // 160000
    const int* src = ei;
    const int* dst = ei + E;

    size_t off = 0;
    auto alloc = [&](size_t bytes) -> void* {
        void* p = (char*)d_ws + off;
        off = (off + bytes + 255) & ~(size_t)255;
        return p;
    };
    int*    deg     = (int*)alloc(sizeof(int) * (size_t)N);
    int*    row_ptr = (int*)alloc(sizeof(int) * (size_t)(N + 1));
    int*    cursor  = (int*)alloc(sizeof(int) * (size_t)N);
    int*    col     = (int*)alloc(sizeof(int) * (size_t)E);
    __bf16* w1b     = (__bf16*)alloc(sizeof(__bf16) * (size_t)D * D);
    __bf16* w2b     = (__bf16*)alloc(sizeof(__bf16) * (size_t)DOUT * D);
    __bf16* xb      = (__bf16*)alloc(sizeof(__bf16) * (size_t)N * D);
    __bf16* t       = (__bf16*)alloc(sizeof(__bf16) * (size_t)N * D);   // x@W1^T
    __bf16* h2      = (__bf16*)alloc(sizeof(__bf16) * (size_t)N * D);   // relu(S t)
    __bf16* u       = (__bf16*)alloc(sizeof(__bf16) * (size_t)N * DOUT); // h2@W2^T

    const int degBlocks = (E + 255) / 256;
    const int xN8 = N * D / 8, w1N8 = D * D / 8, w2N8 = DOUT * D / 8;
    const int cvtBlocks = (xN8 + 255) / 256 + (w1N8 + 255) / 256 + (w2N8 + 255) / 256;

    hipMemsetAsync(deg, 0, sizeof(int) * (size_t)N, stream);
    misc_kernel<<<degBlocks + cvtBlocks, 256, 0, stream>>>(
        dst, deg, E, degBlocks, x, xb, xN8, W1, w1b, w1N8, W2, w2b, w2N8);
    exscan_kernel<<<1, 1024, 0, stream>>>(deg, row_ptr, cursor, N);
    fill_kernel<<<(E + 255) / 256, 256, 0, stream>>>(src, dst, cursor, col, E);

    // t = x @ W1^T  (dense — no gather dependency)
    dim3 g1(D / 128, (N + 127) / 128);
    gemm_mfma_nt<128, 128, 2, 2, false><<<g1, 256, 0, stream>>>(xb, w1b, t, N, D, D);
    // h2 = relu(S t)
    propagate_bf16<true><<<(N + 3) / 4, 256, 0, stream>>>(t, row_ptr, col, h2, N);
    // u = h2 @ W2^T  (64-wide, 2.5 MB -> L2-resident for the final gather)
    dim3 g2(1, (N + 63) / 64);
    gemm_mfma_nt<64, 64, 2, 2, false><<<g2, 256, 0, stream>>>(h2, w2b, u, N, DOUT, D);
    // out = lsm(S u)
    prop2_lsm<<<(N + 3) / 4, 256, 0, stream>>>(u, row_ptr, col, out, N);
}